// Round 6
// baseline (1239.438 us; speedup 1.0000x reference)
//
#include <hip/hip_runtime.h>
#include <hip/hip_cooperative_groups.h>
#include <hip/hip_bf16.h>
#include <cstdint>
#include <cstddef>

namespace cg = cooperative_groups;

#define D_IN  512
#define D_H   128
#define D_OUT 64
#define GRID  512   // mega-kernel blocks; 2/CU co-resident (32KB LDS, <=256 VGPR)
#define SB    512   // stats partial blocks (both paths)

typedef __attribute__((ext_vector_type(8))) short bf16x8;
typedef __attribute__((ext_vector_type(4))) float f32x4;

__device__ __forceinline__ float bf2f(unsigned short u) {
  union { unsigned int i; float f; } v; v.i = ((unsigned int)u) << 16; return v.f;
}
__device__ __forceinline__ unsigned short f2bf(float f) {
  union { unsigned int i; float f; } v; v.f = f;
  unsigned int r = v.i + 0x7FFFu + ((v.i >> 16) & 1u);
  return (unsigned short)(r >> 16);
}
__device__ __forceinline__ unsigned int pk_bf16(float a, float b) {
  union { __hip_bfloat162 h; unsigned int u; } cv;
  cv.h = __float22bfloat162_rn(make_float2(a, b));
  return cv.u;
}

// ---------------- workspace layout (bytes); ws_size ~800MB per R3 profile ----
#define OFF_RP    0u
#define OFF_W0T   400384u
#define OFF_W1TP  531456u
#define OFF_CVEC  547840u
#define OFF_PSUM  548096u     // fp32[512][128]
#define OFF_PSQ   810240u
#define OFF_H     1072384u    // h bf16-packed 100000x128
#define END_H     26672384u   // hw bf16 100000x64 follows
#define END_HW    39472384u

// ============================ MEGA KERNEL ====================================
__global__ __launch_bounds__(256, 2) void gcn_mega(
    const float* __restrict__ x, const float* __restrict__ W0,
    const float* __restrict__ b0, const float* __restrict__ W1,
    const float* __restrict__ b1, const float* __restrict__ adj,
    const int* __restrict__ row, const int* __restrict__ col,
    char* __restrict__ ws, unsigned short* __restrict__ xw16,
    float2* __restrict__ outv, int N, int E) {
  __shared__ union {
    struct { unsigned short A[2][4096]; unsigned short B[2][4096]; } g1;  // 32KB
    struct { float sA[256], sB[256], qA[256], qB[256]; } st;              // 4KB
    struct { unsigned short A[4096]; unsigned short B[2048]; } g2;        // 12KB
    struct { float mean[128]; float istd[128]; } pp;                      // 1KB
  } sh;

  cg::grid_group grid = cg::this_grid();
  const int G   = gridDim.x;
  const int bid = blockIdx.x;
  const int tid = threadIdx.x;
  const int lane = tid & 63;
  const int wave = tid >> 6;
  const int quad = lane >> 4;
  const int l16  = lane & 15;

  int*            rp   = (int*)(ws + OFF_RP);
  unsigned short* W0t  = (unsigned short*)(ws + OFF_W0T);
  unsigned short* W1tp = (unsigned short*)(ws + OFF_W1TP);
  float*          cvec = (float*)(ws + OFF_CVEC);
  float*          psum = (float*)(ws + OFF_PSUM);
  float*          psq  = (float*)(ws + OFF_PSQ);
  unsigned short* h    = (unsigned short*)(ws + OFF_H);
  unsigned int*   h2   = (unsigned int*)h;
  unsigned short* hw   = (unsigned short*)(ws + END_H);
  unsigned int*   hw2  = (unsigned int*)hw;
  unsigned int*   xw2  = (unsigned int*)xw16;

  // ---- stage 0: row_ptr binsearch + W0 transpose ----
  for (int i = bid * 256 + tid; i <= N; i += G * 256) {
    int lo = 0, hi = E;
    while (lo < hi) { int mid = (lo + hi) >> 1; if (row[mid] < i) lo = mid + 1; else hi = mid; }
    rp[i] = lo;
  }
  for (int idx = bid * 256 + tid; idx < D_IN * D_H; idx += G * 256) {
    int k = idx & (D_IN - 1);
    int nn = idx >> 9;
    W0t[nn * D_IN + k] = f2bf(W0[k * D_H + nn]);
  }
  __threadfence(); grid.sync();

  // ---- stage 1: gemm1  xw = x @ W0  (128x128 tile, BK=32, dbuf LDS) ----
  const int T1 = (N + 127) / 128;
  for (int t = bid; t < T1; t += G) {
    const int m0 = t * 128;
    const int wm = (wave >> 1) * 64;
    const int wn = (wave & 1) * 64;
    f32x4 acc[4][4] = {};
    int am[2], ak[2];
    const float* aptr[2];
    const unsigned short* bptr[2];
#pragma unroll
    for (int i = 0; i < 2; ++i) {
      int c = tid + i * 256;
      am[i] = c >> 2; ak[i] = c & 3;
      int gm = m0 + am[i]; if (gm >= N) gm = N - 1;
      aptr[i] = x   + (size_t)gm * D_IN + ak[i] * 8;
      bptr[i] = W0t + (size_t)am[i] * D_IN + ak[i] * 8;
    }
    f32x4 areg[2][2];
    bf16x8 breg[2];
#pragma unroll
    for (int i = 0; i < 2; ++i) {
      areg[i][0] = *(const f32x4*)(aptr[i]);
      areg[i][1] = *(const f32x4*)(aptr[i] + 4);
      breg[i]    = *(const bf16x8*)(bptr[i]);
    }
    const int NIT = D_IN / 32;
    for (int it = 0; it < NIT; ++it) {
      const int buf = it & 1;
      unsigned short* ash = sh.g1.A[buf];
      unsigned short* bsh = sh.g1.B[buf];
#pragma unroll
      for (int i = 0; i < 2; ++i) {
        unsigned int pk4[4];
        pk4[0] = pk_bf16(areg[i][0][0], areg[i][0][1]);
        pk4[1] = pk_bf16(areg[i][0][2], areg[i][0][3]);
        pk4[2] = pk_bf16(areg[i][1][0], areg[i][1][1]);
        pk4[3] = pk_bf16(areg[i][1][2], areg[i][1][3]);
        *(uint4*)&ash[(ak[i] * 128 + am[i]) * 8] = *(uint4*)pk4;
        *(bf16x8*)&bsh[(ak[i] * 128 + am[i]) * 8] = breg[i];
      }
      __syncthreads();
      if (it + 1 < NIT) {
        int k0 = (it + 1) * 32;
#pragma unroll
        for (int i = 0; i < 2; ++i) {
          areg[i][0] = *(const f32x4*)(aptr[i] + k0);
          areg[i][1] = *(const f32x4*)(aptr[i] + k0 + 4);
          breg[i]    = *(const bf16x8*)(bptr[i] + k0);
        }
      }
      bf16x8 af[4], bfv[4];
#pragma unroll
      for (int mf = 0; mf < 4; ++mf)
        af[mf] = *(const bf16x8*)&ash[(quad * 128 + (wm + mf * 16 + l16)) * 8];
#pragma unroll
      for (int nf = 0; nf < 4; ++nf)
        bfv[nf] = *(const bf16x8*)&bsh[(quad * 128 + (wn + nf * 16 + l16)) * 8];
#pragma unroll
      for (int mf = 0; mf < 4; ++mf)
#pragma unroll
        for (int nf = 0; nf < 4; ++nf)
          acc[mf][nf] = __builtin_amdgcn_mfma_f32_16x16x32_bf16(af[mf], bfv[nf], acc[mf][nf], 0, 0, 0);
    }
    // C/D layout: row = quad*4 + i, col = lane&15 [m89/m91-verified]
#pragma unroll
    for (int mf = 0; mf < 4; ++mf)
#pragma unroll
      for (int nf = 0; nf < 4; ++nf)
#pragma unroll
        for (int i = 0; i < 4; ++i) {
          int r = m0 + wm + mf * 16 + quad * 4 + i;
          int cc = wn + nf * 16 + l16;
          if (r < N) xw16[(size_t)r * D_H + cc] = f2bf(acc[mf][nf][i]);
        }
    __syncthreads();
  }
  __threadfence(); grid.sync();

  // ---- stage 2: spmm1 + fused BN-stats partials ----
  {
    float s0 = 0.f, s1 = 0.f, q0 = 0.f, q1 = 0.f;
    const int VB = (N + 3) / 4;
    for (int vb = bid; vb < VB; vb += G) {
      int node = vb * 4 + wave;
      if (node >= N) continue;
      int e0 = rp[node], e1 = rp[node + 1];
      float a0 = 0.f, a1 = 0.f;
      for (int e = e0; e < e1; e += 16) {
        int idx[16]; float w[16];
#pragma unroll
        for (int j = 0; j < 16; ++j) {
          int ee = e + j;
          int ec = ee < e1 ? ee : e0;
          idx[j] = col[ec];
          w[j] = ee < e1 ? adj[ec] : 0.f;
        }
#pragma unroll
        for (int j = 0; j < 16; ++j) {
          unsigned int p = xw2[(size_t)idx[j] * 64 + lane];
          a0 += w[j] * bf2f((unsigned short)(p & 0xFFFF));
          a1 += w[j] * bf2f((unsigned short)(p >> 16));
        }
      }
      float r0 = fmaxf(a0 + b0[2 * lane], 0.f);
      float r1 = fmaxf(a1 + b0[2 * lane + 1], 0.f);
      h2[(size_t)node * 64 + lane] = ((unsigned int)f2bf(r1) << 16) | (unsigned int)f2bf(r0);
      // stats on stored (bf16-rounded) values? reference uses exact h; use fp32
      // pre-round values — matches reference arithmetic more closely.
      s0 += r0; s1 += r1; q0 += r0 * r0; q1 += r1 * r1;
    }
    sh.st.sA[tid] = s0; sh.st.sB[tid] = s1; sh.st.qA[tid] = q0; sh.st.qB[tid] = q1;
    __syncthreads();
    if (tid < 64) {
      float S0 = sh.st.sA[tid] + sh.st.sA[tid + 64] + sh.st.sA[tid + 128] + sh.st.sA[tid + 192];
      float S1 = sh.st.sB[tid] + sh.st.sB[tid + 64] + sh.st.sB[tid + 128] + sh.st.sB[tid + 192];
      float Q0 = sh.st.qA[tid] + sh.st.qA[tid + 64] + sh.st.qA[tid + 128] + sh.st.qA[tid + 192];
      float Q1 = sh.st.qB[tid] + sh.st.qB[tid + 64] + sh.st.qB[tid + 128] + sh.st.qB[tid + 192];
      psum[bid * 128 + 2 * tid]     = S0;
      psum[bid * 128 + 2 * tid + 1] = S1;
      psq [bid * 128 + 2 * tid]     = Q0;
      psq [bid * 128 + 2 * tid + 1] = Q1;
    }
  }
  __threadfence(); grid.sync();

  // ---- stage 3: prep (block 0): mean/istd -> W1', cvec ----
  if (bid == 0) {
    if (tid < 128) {
      float s = 0.f, q = 0.f;
      for (int b = 0; b < G; ++b) { s += psum[b * 128 + tid]; q += psq[b * 128 + tid]; }
      float m = s / (float)N;
      float var = q / (float)N - m * m;
      if (var < 0.f) var = 0.f;
      sh.pp.mean[tid] = m;
      sh.pp.istd[tid] = rsqrtf(var + 1e-5f);
    }
    __syncthreads();
    for (int idx = tid; idx < D_OUT * D_H; idx += 256) {
      int nn = idx >> 7, k = idx & 127;
      W1tp[nn * D_H + k] = f2bf(sh.pp.istd[k] * W1[k * D_OUT + nn]);
    }
    if (tid < D_OUT) {
      float a = 0.f;
      for (int k = 0; k < D_H; ++k) a += sh.pp.mean[k] * sh.pp.istd[k] * W1[k * D_OUT + tid];
      cvec[tid] = -a;
    }
  }
  __threadfence(); grid.sync();

  // ---- stage 4: gemm2  hw = h @ W1' + c  (128x64 tile, BK=32) ----
  for (int t = bid; t < T1; t += G) {
    const int m0 = t * 128;
    const int wm = wave * 32;
    f32x4 acc[2][4] = {};
    for (int k0 = 0; k0 < D_H; k0 += 32) {
      __syncthreads();
#pragma unroll
      for (int i = 0; i < 2; ++i) {
        int c = tid + i * 256;
        int m = c >> 2, k8 = c & 3;
        int gm = m0 + m; if (gm >= N) gm = N - 1;
        *(bf16x8*)&sh.g2.A[(k8 * 128 + m) * 8] =
            *(const bf16x8*)&h[(size_t)gm * D_H + k0 + k8 * 8];
      }
      {
        int nn = tid >> 2, k8 = tid & 3;
        *(bf16x8*)&sh.g2.B[(k8 * 64 + nn) * 8] =
            *(const bf16x8*)&W1tp[(size_t)nn * D_H + k0 + k8 * 8];
      }
      __syncthreads();
      bf16x8 af[2], bfv[4];
#pragma unroll
      for (int mf = 0; mf < 2; ++mf)
        af[mf] = *(const bf16x8*)&sh.g2.A[(quad * 128 + (wm + mf * 16 + l16)) * 8];
#pragma unroll
      for (int nf = 0; nf < 4; ++nf)
        bfv[nf] = *(const bf16x8*)&sh.g2.B[(quad * 64 + (nf * 16 + l16)) * 8];
#pragma unroll
      for (int mf = 0; mf < 2; ++mf)
#pragma unroll
        for (int nf = 0; nf < 4; ++nf)
          acc[mf][nf] = __builtin_amdgcn_mfma_f32_16x16x32_bf16(af[mf], bfv[nf], acc[mf][nf], 0, 0, 0);
    }
#pragma unroll
    for (int mf = 0; mf < 2; ++mf)
#pragma unroll
      for (int nf = 0; nf < 4; ++nf)
#pragma unroll
        for (int i = 0; i < 4; ++i) {
          int r = m0 + wm + mf * 16 + quad * 4 + i;
          int cc = nf * 16 + l16;
          if (r < N) hw[(size_t)r * 64 + cc] = f2bf(acc[mf][nf][i] + cvec[cc]);
        }
    __syncthreads();
  }
  __threadfence(); grid.sync();

  // ---- stage 5: spmm2  out = adj @ hw + b1 ----
  {
    const int VB = (N + 7) / 8;
    const int hwv = tid >> 5;       // 8 half-waves
    const int l   = tid & 31;
    for (int vb = bid; vb < VB; vb += G) {
      int node = vb * 8 + hwv;
      if (node >= N) continue;
      int e0 = rp[node], e1 = rp[node + 1];
      float a0 = 0.f, a1 = 0.f;
      for (int e = e0; e < e1; e += 16) {
        int idx[16]; float w[16];
#pragma unroll
        for (int j = 0; j < 16; ++j) {
          int ee = e + j;
          int ec = ee < e1 ? ee : e0;
          idx[j] = col[ec];
          w[j] = ee < e1 ? adj[ec] : 0.f;
        }
#pragma unroll
        for (int j = 0; j < 16; ++j) {
          unsigned int p = hw2[(size_t)idx[j] * 32 + l];
          a0 += w[j] * bf2f((unsigned short)(p & 0xFFFF));
          a1 += w[j] * bf2f((unsigned short)(p >> 16));
        }
      }
      float2 r; r.x = a0 + b1[2 * l]; r.y = a1 + b1[2 * l + 1];
      outv[(size_t)node * 32 + l] = r;
    }
  }
}

// ===================== FALLBACK PIPELINE (R5, known-good) ====================
__global__ void k_init(const int* __restrict__ row, int* __restrict__ rp,
                       const float* __restrict__ W0, unsigned short* __restrict__ W0t,
                       int n, int e, int RB) {
  int b = blockIdx.x, t = threadIdx.x;
  if (b < RB) {
    int i = b * 256 + t;
    if (i > n) return;
    int lo = 0, hi = e;
    while (lo < hi) { int mid = (lo + hi) >> 1; if (row[mid] < i) lo = mid + 1; else hi = mid; }
    rp[i] = lo;
  } else {
    int idx = (b - RB) * 256 + t;
    int k = idx & (D_IN - 1);
    int nn = idx >> 9;
    W0t[nn * D_IN + k] = f2bf(W0[k * D_H + nn]);
  }
}

__global__ __launch_bounds__(256) void k_gemm1(const float* __restrict__ A,
                                               const unsigned short* __restrict__ Bt,
                                               unsigned short* __restrict__ C, int M) {
  __shared__ unsigned short Ash[2][4096];
  __shared__ unsigned short Bsh[2][4096];
  const int tid = threadIdx.x, lane = tid & 63, wave = tid >> 6;
  const int wm = (wave >> 1) * 64, wn = (wave & 1) * 64;
  const int m0 = blockIdx.x * 128, quad = lane >> 4, l16 = lane & 15;
  f32x4 acc[4][4] = {};
  int am[2], ak[2];
  const float* aptr[2];
  const unsigned short* bptr[2];
#pragma unroll
  for (int i = 0; i < 2; ++i) {
    int c = tid + i * 256;
    am[i] = c >> 2; ak[i] = c & 3;
    int gm = m0 + am[i]; if (gm >= M) gm = M - 1;
    aptr[i] = A + (size_t)gm * D_IN + ak[i] * 8;
    bptr[i] = Bt + (size_t)am[i] * D_IN + ak[i] * 8;
  }
  f32x4 areg[2][2]; bf16x8 breg[2];
#pragma unroll
  for (int i = 0; i < 2; ++i) {
    areg[i][0] = *(const f32x4*)(aptr[i]);
    areg[i][1] = *(const f32x4*)(aptr[i] + 4);
    breg[i]    = *(const bf16x8*)(bptr[i]);
  }
  const int NIT = D_IN / 32;
  for (int it = 0; it < NIT; ++it) {
    const int buf = it & 1;
    unsigned short* ash = Ash[buf];
    unsigned short* bsh = Bsh[buf];
#pragma unroll
    for (int i = 0; i < 2; ++i) {
      unsigned int pk4[4];
      pk4[0] = pk_bf16(areg[i][0][0], areg[i][0][1]);
      pk4[1] = pk_bf16(areg[i][0][2], areg[i][0][3]);
      pk4[2] = pk_bf16(areg[i][1][0], areg[i][1][1]);
      pk4[3] = pk_bf16(areg[i][1][2], areg[i][1][3]);
      *(uint4*)&ash[(ak[i] * 128 + am[i]) * 8] = *(uint4*)pk4;
      *(bf16x8*)&bsh[(ak[i] * 128 + am[i]) * 8] = breg[i];
    }
    __syncthreads();
    if (it + 1 < NIT) {
      int k0 = (it + 1) * 32;
#pragma unroll
      for (int i = 0; i < 2; ++i) {
        areg[i][0] = *(const f32x4*)(aptr[i] + k0);
        areg[i][1] = *(const f32x4*)(aptr[i] + k0 + 4);
        breg[i]    = *(const bf16x8*)(bptr[i] + k0);
      }
    }
    bf16x8 af[4], bfv[4];
#pragma unroll
    for (int mf = 0; mf < 4; ++mf)
      af[mf] = *(const bf16x8*)&ash[(quad * 128 + (wm + mf * 16 + l16)) * 8];
#pragma unroll
    for (int nf = 0; nf < 4; ++nf)
      bfv[nf] = *(const bf16x8*)&bsh[(quad * 128 + (wn + nf * 16 + l16)) * 8];
#pragma unroll
    for (int mf = 0; mf < 4; ++mf)
#pragma unroll
      for (int nf = 0; nf < 4; ++nf)
        acc[mf][nf] = __builtin_amdgcn_mfma_f32_16x16x32_bf16(af[mf], bfv[nf], acc[mf][nf], 0, 0, 0);
  }
#pragma unroll
  for (int mf = 0; mf < 4; ++mf)
#pragma unroll
    for (int nf = 0; nf < 4; ++nf)
#pragma unroll
      for (int i = 0; i < 4; ++i) {
        int r = m0 + wm + mf * 16 + quad * 4 + i;
        int cc = wn + nf * 16 + l16;
        if (r < M) C[(size_t)r * D_H + cc] = f2bf(acc[mf][nf][i]);
      }
}

__global__ __launch_bounds__(256) void k_spmm1(const unsigned int* __restrict__ xw2,
                                               const float* __restrict__ adj,
                                               const int* __restrict__ col,
                                               const int* __restrict__ rp,
                                               const float* __restrict__ b0,
                                               unsigned int* __restrict__ h2, int n) {
  int node = blockIdx.x * 4 + (threadIdx.x >> 6);
  if (node >= n) return;
  int l = threadIdx.x & 63;
  int e0 = rp[node], e1 = rp[node + 1];
  float a0 = 0.f, a1 = 0.f;
  for (int e = e0; e < e1; e += 16) {
    int idx[16]; float w[16];
#pragma unroll
    for (int j = 0; j < 16; ++j) {
      int ee = e + j;
      int ec = ee < e1 ? ee : e0;
      idx[j] = col[ec];
      w[j] = ee < e1 ? adj[ec] : 0.f;
    }
#pragma unroll
    for (int j = 0; j < 16; ++j) {
      unsigned int p = xw2[(size_t)idx[j] * 64 + l];
      a0 += w[j] * bf2f((unsigned short)(p & 0xFFFF));
      a1 += w[j] * bf2f((unsigned short)(p >> 16));
    }
  }
  float r0 = fmaxf(a0 + b0[2 * l], 0.f);
  float r1 = fmaxf(a1 + b0[2 * l + 1], 0.f);
  h2[(size_t)node * 64 + l] = ((unsigned int)f2bf(r1) << 16) | (unsigned int)f2bf(r0);
}

__global__ __launch_bounds__(256) void k_stats(const unsigned int* __restrict__ h2,
                                               float* __restrict__ psum,
                                               float* __restrict__ psq, int n) {
  __shared__ float sA[256], sB[256], qA[256], qB[256];
  int t = threadIdx.x;
  int f2 = t & 63, rg = t >> 6;
  float s0 = 0.f, s1 = 0.f, q0 = 0.f, q1 = 0.f;
  for (int r = blockIdx.x * 4 + rg; r < n; r += gridDim.x * 4) {
    unsigned int p = h2[(size_t)r * 64 + f2];
    float v0 = bf2f((unsigned short)(p & 0xFFFF));
    float v1 = bf2f((unsigned short)(p >> 16));
    s0 += v0; s1 += v1; q0 += v0 * v0; q1 += v1 * v1;
  }
  sA[t] = s0; sB[t] = s1; qA[t] = q0; qB[t] = q1;
  __syncthreads();
  if (t < 64) {
    float S0 = sA[t] + sA[t + 64] + sA[t + 128] + sA[t + 192];
    float S1 = sB[t] + sB[t + 64] + sB[t + 128] + sB[t + 192];
    float Q0 = qA[t] + qA[t + 64] + qA[t + 128] + qA[t + 192];
    float Q1 = qB[t] + qB[t + 64] + qB[t + 128] + qB[t + 192];
    psum[blockIdx.x * 128 + 2 * t]     = S0;
    psum[blockIdx.x * 128 + 2 * t + 1] = S1;
    psq [blockIdx.x * 128 + 2 * t]     = Q0;
    psq [blockIdx.x * 128 + 2 * t + 1] = Q1;
  }
}

__global__ void k_prep2(const float* __restrict__ psum, const float* __restrict__ psq,
                        const float* __restrict__ W1,
                        unsigned short* __restrict__ W1tp, float* __restrict__ cvec, int n) {
  __shared__ float mean_s[128], istd_s[128];
  int t = threadIdx.x;
  if (t < 128) {
    float s = 0.f, q = 0.f;
#pragma unroll 4
    for (int b = 0; b < SB; ++b) { s += psum[b * 128 + t]; q += psq[b * 128 + t]; }
    float m = s / (float)n;
    float var = q / (float)n - m * m;
    if (var < 0.f) var = 0.f;
    mean_s[t] = m;
    istd_s[t] = rsqrtf(var + 1e-5f);
  }
  __syncthreads();
  for (int idx = t; idx < D_OUT * D_H; idx += 256) {
    int nn = idx >> 7, k = idx & 127;
    W1tp[nn * D_H + k] = f2bf(istd_s[k] * W1[k * D_OUT + nn]);
  }
  if (t < D_OUT) {
    float a = 0.f;
    for (int k = 0; k < D_H; ++k) a += mean_s[k] * istd_s[k] * W1[k * D_OUT + t];
    cvec[t] = -a;
  }
}

__global__ __launch_bounds__(256) void k_gemm2(const unsigned short* __restrict__ A,
                                               const unsigned short* __restrict__ Bt,
                                               const float* __restrict__ cvec,
                                               unsigned short* __restrict__ Cout, int M) {
  __shared__ unsigned short Ash[4096];
  __shared__ unsigned short Bsh[2048];
  const int tid = threadIdx.x, lane = tid & 63, wave = tid >> 6;
  const int wm = wave * 32, m0 = blockIdx.x * 128;
  const int quad = lane >> 4, l16 = lane & 15;
  f32x4 acc[2][4] = {};
  for (int k0 = 0; k0 < D_H; k0 += 32) {
    __syncthreads();
#pragma unroll
    for (int i = 0; i < 2; ++i) {
      int c = tid + i * 256;
      int m = c >> 2, k8 = c & 3;
      int gm = m0 + m; if (gm >= M) gm = M - 1;
      *(bf16x8*)&Ash[(k8 * 128 + m) * 8] = *(const bf16x8*)&A[(size_t)gm * D_H + k0 + k8 * 8];
    }
    {
      int nn = tid >> 2, k8 = tid & 3;
      *(bf16x8*)&Bsh[(k8 * 64 + nn) * 8] = *(const bf16x8*)&Bt[(size_t)nn * D_H + k0 + k8 * 8];
    }
    __syncthreads();
    bf16x8 af[2], bfv[4];
#pragma unroll
    for (int mf = 0; mf < 2; ++mf)
      af[mf] = *(const bf16x8*)&Ash[(quad * 128 + (wm + mf * 16 + l16)) * 8];
#pragma unroll
    for (int nf = 0; nf < 4; ++nf)
      bfv[nf] = *(const bf16x8*)&Bsh[(quad * 64 + (nf * 16 + l16)) * 8];
#pragma unroll
    for (int mf = 0; mf < 2; ++mf)
#pragma unroll
      for (int nf = 0; nf < 4; ++nf)
        acc[mf][nf] = __builtin_amdgcn_mfma_f32_16x16x32_bf16(af[mf], bfv[nf], acc[mf][nf], 0, 0, 0);
  }
#pragma unroll
  for (int mf = 0; mf < 2; ++mf)
#pragma unroll
    for (int nf = 0; nf < 4; ++nf)
#pragma unroll
      for (int i = 0; i < 4; ++i) {
        int r = m0 + wm + mf * 16 + quad * 4 + i;
        int cc = nf * 16 + l16;
        if (r < M) Cout[(size_t)r * 64 + cc] = f2bf(acc[mf][nf][i] + cvec[cc]);
      }
}

__global__ __launch_bounds__(256) void k_spmm2(const unsigned int* __restrict__ hw2,
                                               const float* __restrict__ adj,
                                               const int* __restrict__ col,
                                               const int* __restrict__ rp,
                                               const float* __restrict__ b1,
                                               float2* __restrict__ o2, int n) {
  int node = blockIdx.x * 8 + (threadIdx.x >> 5);
  if (node >= n) return;
  int l = threadIdx.x & 31;
  int e0 = rp[node], e1 = rp[node + 1];
  float a0 = 0.f, a1 = 0.f;
  for (int e = e0; e < e1; e += 16) {
    int idx[16]; float w[16];
#pragma unroll
    for (int j = 0; j < 16; ++j) {
      int ee = e + j;
      int ec = ee < e1 ? ee : e0;
      idx[j] = col[ec];
      w[j] = ee < e1 ? adj[ec] : 0.f;
    }
#pragma unroll
    for (int j = 0; j < 16; ++j) {
      unsigned int p = hw2[(size_t)idx[j] * 32 + l];
      a0 += w[j] * bf2f((unsigned short)(p & 0xFFFF));
      a1 += w[j] * bf2f((unsigned short)(p >> 16));
    }
  }
  float2 r; r.x = a0 + b1[2 * l]; r.y = a1 + b1[2 * l + 1];
  o2[(size_t)node * 32 + l] = r;
}

extern "C" void kernel_launch(void* const* d_in, const int* in_sizes, int n_in,
                              void* d_out, int out_size, void* d_ws, size_t ws_size,
                              hipStream_t stream) {
  const float* x   = (const float*)d_in[0];
  const float* W0  = (const float*)d_in[1];
  const float* b0  = (const float*)d_in[2];
  const float* W1  = (const float*)d_in[3];
  const float* b1  = (const float*)d_in[4];
  const float* adj = (const float*)d_in[5];
  const int* row = (const int*)d_in[6];
  const int* col = (const int*)d_in[7];
  int N = in_sizes[0] / D_IN;
  int E = in_sizes[5];

  char* ws = (char*)d_ws;
  unsigned short* xw16 = (unsigned short*)d_out;
  float2*         outv = (float2*)d_out;

  // ---- preferred: single cooperative mega-kernel ----
  if (ws_size >= (size_t)END_HW) {
    void* args[] = {(void*)&x, (void*)&W0, (void*)&b0, (void*)&W1, (void*)&b1,
                    (void*)&adj, (void*)&row, (void*)&col, (void*)&ws,
                    (void*)&xw16, (void*)&outv, (void*)&N, (void*)&E};
    hipError_t err = hipLaunchCooperativeKernel((void*)gcn_mega, dim3(GRID), dim3(256),
                                                args, 0, stream);
    if (err == hipSuccess) return;
    (void)hipGetLastError();  // clear; fall through to multi-kernel path
  }

  // ---- fallback: R5 multi-kernel pipeline ----
  int*            rp   = (int*)(ws + OFF_RP);
  unsigned short* W0t  = (unsigned short*)(ws + OFF_W0T);
  unsigned short* W1tp = (unsigned short*)(ws + OFF_W1TP);
  float*          cvec = (float*)(ws + OFF_CVEC);
  float*          psum = (float*)(ws + OFF_PSUM);
  float*          psq  = (float*)(ws + OFF_PSQ);
  unsigned short* h    = (unsigned short*)(ws + OFF_H);

  const bool hw_in_ws = (ws_size >= (size_t)END_HW);
  unsigned short* hwp  = hw_in_ws ? (unsigned short*)(ws + END_H) : (unsigned short*)d_out;
  float*          outd = hw_in_ws ? (float*)d_out                 : (float*)(ws + OFF_H);

  const int RB = (N + 1 + 255) / 256;
  const int TB = (D_IN * D_H) / 256;
  k_init<<<RB + TB, 256, 0, stream>>>(row, rp, W0, W0t, N, E, RB);
  k_gemm1<<<(N + 127) / 128, 256, 0, stream>>>(x, W0t, xw16, N);
  k_spmm1<<<(N + 3) / 4, 256, 0, stream>>>((const unsigned int*)xw16, adj, col, rp, b0,
                                           (unsigned int*)h, N);
  k_stats<<<SB, 256, 0, stream>>>((const unsigned int*)h, psum, psq, N);
  k_prep2<<<1, 256, 0, stream>>>(psum, psq, W1, W1tp, cvec, N);
  k_gemm2<<<(N + 127) / 128, 256, 0, stream>>>(h, W1tp, cvec, hwp, N);
  k_spmm2<<<(N + 7) / 8, 256, 0, stream>>>((const unsigned int*)hwp, adj, col, rp, b1,
                                           (float2*)outd, N);
  if (!hw_in_ws) {
    hipMemcpyAsync(d_out, outd, (size_t)N * D_OUT * sizeof(float),
                   hipMemcpyDeviceToDevice, stream);
  }
}

// Round 7
// 478.662 us; speedup vs baseline: 2.5894x; 2.5894x over previous
//
#include <hip/hip_runtime.h>
#include <hip/hip_bf16.h>
#include <cstdint>
#include <cstddef>

#define D_IN  512
#define D_H   128
#define D_OUT 64
#define SB    256   // stats partial blocks (1 per CU)

typedef __attribute__((ext_vector_type(8))) short bf16x8;
typedef __attribute__((ext_vector_type(4))) float f32x4;

__device__ __forceinline__ float bf2f(unsigned short u) {
  union { unsigned int i; float f; } v; v.i = ((unsigned int)u) << 16; return v.f;
}
__device__ __forceinline__ unsigned short f2bf(float f) {
  union { unsigned int i; float f; } v; v.f = f;
  unsigned int r = v.i + 0x7FFFu + ((v.i >> 16) & 1u);
  return (unsigned short)(r >> 16);
}
__device__ __forceinline__ unsigned int pk_bf16(float a, float b) {
  union { __hip_bfloat162 h; unsigned int u; } cv;
  cv.h = __float22bfloat162_rn(make_float2(a, b));
  return cv.u;
}

// ---------------- workspace layout (bytes); ws_size ~800MB (R3/R6 profile) ---
#define OFF_RP    0u          // row_ptr int32[100001]
#define OFF_W0T   400384u     // W0^T bf16 128x512
#define OFF_W1TP  531456u     // W1'^T bf16 64x128
#define OFF_CVEC  547840u     // fp32[64]
#define OFF_PSUM  548096u     // fp32[SB][128]
#define OFF_PSQ   679168u     // fp32[SB][128]
#define OFF_H     810240u     // h bf16-packed 100000x128
#define END_H     26410240u
#define END_HW    39210240u   // + hw bf16 100000x64

// ---- k_init: [0,RB) row_ptr binsearch | [RB,..) W0 transpose ---------------
__global__ void k_init(const int* __restrict__ row, int* __restrict__ rp,
                       const float* __restrict__ W0, unsigned short* __restrict__ W0t,
                       int n, int e, int RB) {
  int b = blockIdx.x, t = threadIdx.x;
  if (b < RB) {
    int i = b * 256 + t;
    if (i > n) return;
    int lo = 0, hi = e;
    while (lo < hi) { int mid = (lo + hi) >> 1; if (row[mid] < i) lo = mid + 1; else hi = mid; }
    rp[i] = lo;
  } else {
    int idx = (b - RB) * 256 + t;          // 65536 total
    int k = idx & (D_IN - 1);
    int nn = idx >> 9;
    W0t[nn * D_IN + k] = f2bf(W0[k * D_H + nn]);
  }
}

// ---- GEMM1: xw(bf16) = x(fp32) @ W0. tile 128x128, BK=32, dbuf LDS, 1 barrier
__global__ __launch_bounds__(256) void k_gemm1(const float* __restrict__ A,
                                               const unsigned short* __restrict__ Bt,
                                               unsigned short* __restrict__ C, int M) {
  __shared__ unsigned short Ash[2][4096];
  __shared__ unsigned short Bsh[2][4096];
  const int tid = threadIdx.x, lane = tid & 63, wave = tid >> 6;
  const int wm = (wave >> 1) * 64, wn = (wave & 1) * 64;
  const int m0 = blockIdx.x * 128, quad = lane >> 4, l16 = lane & 15;
  f32x4 acc[4][4] = {};
  int am[2], ak[2];
  const float* aptr[2];
  const unsigned short* bptr[2];
#pragma unroll
  for (int i = 0; i < 2; ++i) {
    int c = tid + i * 256;
    am[i] = c >> 2; ak[i] = c & 3;
    int gm = m0 + am[i]; if (gm >= M) gm = M - 1;
    aptr[i] = A + (size_t)gm * D_IN + ak[i] * 8;
    bptr[i] = Bt + (size_t)am[i] * D_IN + ak[i] * 8;
  }
  f32x4 areg[2][2]; bf16x8 breg[2];
#pragma unroll
  for (int i = 0; i < 2; ++i) {
    areg[i][0] = *(const f32x4*)(aptr[i]);
    areg[i][1] = *(const f32x4*)(aptr[i] + 4);
    breg[i]    = *(const bf16x8*)(bptr[i]);
  }
  const int NIT = D_IN / 32;
  for (int it = 0; it < NIT; ++it) {
    const int buf = it & 1;
    unsigned short* ash = Ash[buf];
    unsigned short* bsh = Bsh[buf];
#pragma unroll
    for (int i = 0; i < 2; ++i) {
      unsigned int pk4[4];
      pk4[0] = pk_bf16(areg[i][0][0], areg[i][0][1]);
      pk4[1] = pk_bf16(areg[i][0][2], areg[i][0][3]);
      pk4[2] = pk_bf16(areg[i][1][0], areg[i][1][1]);
      pk4[3] = pk_bf16(areg[i][1][2], areg[i][1][3]);
      *(uint4*)&ash[(ak[i] * 128 + am[i]) * 8] = *(uint4*)pk4;
      *(bf16x8*)&bsh[(ak[i] * 128 + am[i]) * 8] = breg[i];
    }
    __syncthreads();
    if (it + 1 < NIT) {
      int k0 = (it + 1) * 32;
#pragma unroll
      for (int i = 0; i < 2; ++i) {
        areg[i][0] = *(const f32x4*)(aptr[i] + k0);
        areg[i][1] = *(const f32x4*)(aptr[i] + k0 + 4);
        breg[i]    = *(const bf16x8*)(bptr[i] + k0);
      }
    }
    bf16x8 af[4], bfv[4];
#pragma unroll
    for (int mf = 0; mf < 4; ++mf)
      af[mf] = *(const bf16x8*)&ash[(quad * 128 + (wm + mf * 16 + l16)) * 8];
#pragma unroll
    for (int nf = 0; nf < 4; ++nf)
      bfv[nf] = *(const bf16x8*)&bsh[(quad * 128 + (wn + nf * 16 + l16)) * 8];
#pragma unroll
    for (int mf = 0; mf < 4; ++mf)
#pragma unroll
      for (int nf = 0; nf < 4; ++nf)
        acc[mf][nf] = __builtin_amdgcn_mfma_f32_16x16x32_bf16(af[mf], bfv[nf], acc[mf][nf], 0, 0, 0);
  }
  // C/D layout: row = quad*4 + i, col = lane&15 [m89/m91-verified]
#pragma unroll
  for (int mf = 0; mf < 4; ++mf)
#pragma unroll
    for (int nf = 0; nf < 4; ++nf)
#pragma unroll
      for (int i = 0; i < 4; ++i) {
        int r = m0 + wm + mf * 16 + quad * 4 + i;
        int cc = wn + nf * 16 + l16;
        if (r < M) C[(size_t)r * D_H + cc] = f2bf(acc[mf][nf][i]);
      }
}

// ---- SpMM1: h = relu(adj @ xw + b0); one wave/node.
// Edge metadata via 2 coalesced loads (lanes&7) + __shfl broadcast:
// 10 VMEM insts per 8-edge round instead of 24.
__global__ __launch_bounds__(256) void k_spmm1(const unsigned int* __restrict__ xw2,
                                               const float* __restrict__ adj,
                                               const int* __restrict__ col,
                                               const int* __restrict__ rp,
                                               const float* __restrict__ b0,
                                               unsigned int* __restrict__ h2, int n) {
  int node = blockIdx.x * 4 + (threadIdx.x >> 6);
  if (node >= n) return;
  int l = threadIdx.x & 63;
  int e0 = rp[node], e1 = rp[node + 1];
  float a0 = 0.f, a1 = 0.f;
  for (int e = e0; e < e1; e += 8) {
    int ee = e + (l & 7);
    int ec = ee < e1 ? ee : e1 - 1;
    int   cl = col[ec];
    float vl = ee < e1 ? adj[ec] : 0.f;
#pragma unroll
    for (int j = 0; j < 8; ++j) {
      int   cj = __shfl(cl, j, 64);
      float wj = __shfl(vl, j, 64);
      unsigned int p = xw2[(size_t)cj * 64 + l];
      a0 += wj * bf2f((unsigned short)(p & 0xFFFF));
      a1 += wj * bf2f((unsigned short)(p >> 16));
    }
  }
  float r0 = fmaxf(a0 + b0[2 * l], 0.f);
  float r1 = fmaxf(a1 + b0[2 * l + 1], 0.f);
  h2[(size_t)node * 64 + l] = ((unsigned int)f2bf(r1) << 16) | (unsigned int)f2bf(r0);
}

// ---- BN stats: SB=256 per-block partials (no atomics) -----------------------
__global__ __launch_bounds__(256) void k_stats(const unsigned int* __restrict__ h2,
                                               float* __restrict__ psum,
                                               float* __restrict__ psq, int n) {
  __shared__ float sA[256], sB[256], qA[256], qB[256];
  int t = threadIdx.x;
  int f2 = t & 63, rg = t >> 6;
  float s0 = 0.f, s1 = 0.f, q0 = 0.f, q1 = 0.f;
  for (int r = blockIdx.x * 4 + rg; r < n; r += gridDim.x * 4) {
    unsigned int p = h2[(size_t)r * 64 + f2];
    float v0 = bf2f((unsigned short)(p & 0xFFFF));
    float v1 = bf2f((unsigned short)(p >> 16));
    s0 += v0; s1 += v1; q0 += v0 * v0; q1 += v1 * v1;
  }
  sA[t] = s0; sB[t] = s1; qA[t] = q0; qB[t] = q1;
  __syncthreads();
  if (t < 64) {
    float S0 = sA[t] + sA[t + 64] + sA[t + 128] + sA[t + 192];
    float S1 = sB[t] + sB[t + 64] + sB[t + 128] + sB[t + 192];
    float Q0 = qA[t] + qA[t + 64] + qA[t + 128] + qA[t + 192];
    float Q1 = qB[t] + qB[t + 64] + qB[t + 128] + qB[t + 192];
    psum[blockIdx.x * 128 + 2 * t]     = S0;
    psum[blockIdx.x * 128 + 2 * t + 1] = S1;
    psq [blockIdx.x * 128 + 2 * t]     = Q0;
    psq [blockIdx.x * 128 + 2 * t + 1] = Q1;
  }
}

// ---- prep2: PARALLEL partial reduce -> mean/istd -> W1', cvec ---------------
__global__ void k_prep2(const float* __restrict__ psum, const float* __restrict__ psq,
                        const float* __restrict__ W1,
                        unsigned short* __restrict__ W1tp, float* __restrict__ cvec, int n) {
  __shared__ float rs[256], rq[256];
  __shared__ float mean_s[128], istd_s[128];
  __shared__ float cpart[256];
  int t = threadIdx.x;            // 256
  int f = t & 127, half = t >> 7; // each (f,half) sums SB/2 blocks
  {
    float s = 0.f, q = 0.f;
#pragma unroll 8
    for (int b = half * (SB / 2); b < (half + 1) * (SB / 2); ++b) {
      s += psum[b * 128 + f]; q += psq[b * 128 + f];
    }
    rs[t] = s; rq[t] = q;
  }
  __syncthreads();
  if (t < 128) {
    float s = rs[t] + rs[t + 128];
    float q = rq[t] + rq[t + 128];
    float m = s / (float)n;
    float var = q / (float)n - m * m;
    if (var < 0.f) var = 0.f;
    mean_s[t] = m;
    istd_s[t] = rsqrtf(var + 1e-5f);
  }
  __syncthreads();
  for (int idx = t; idx < D_OUT * D_H; idx += 256) {
    int nn = idx >> 7, k = idx & 127;
    W1tp[nn * D_H + k] = f2bf(istd_s[k] * W1[k * D_OUT + nn]);
  }
  {  // cvec: 4 partials per output column
    int o = t & 63, part = t >> 6;
    float a = 0.f;
    for (int k = part * 32; k < part * 32 + 32; ++k)
      a += mean_s[k] * istd_s[k] * W1[k * D_OUT + o];
    cpart[t] = a;
  }
  __syncthreads();
  if (t < D_OUT)
    cvec[t] = -(cpart[t] + cpart[t + 64] + cpart[t + 128] + cpart[t + 192]);
}

// ---- GEMM2: hw(bf16) = h(bf16) @ W1' + c. tile 128x64, BK=32 ----------------
__global__ __launch_bounds__(256) void k_gemm2(const unsigned short* __restrict__ A,
                                               const unsigned short* __restrict__ Bt,
                                               const float* __restrict__ cvec,
                                               unsigned short* __restrict__ Cout, int M) {
  __shared__ unsigned short Ash[4096];
  __shared__ unsigned short Bsh[2048];
  const int tid = threadIdx.x, lane = tid & 63, wave = tid >> 6;
  const int wm = wave * 32, m0 = blockIdx.x * 128;
  const int quad = lane >> 4, l16 = lane & 15;
  f32x4 acc[2][4] = {};
  for (int k0 = 0; k0 < D_H; k0 += 32) {
    __syncthreads();
#pragma unroll
    for (int i = 0; i < 2; ++i) {
      int c = tid + i * 256;
      int m = c >> 2, k8 = c & 3;
      int gm = m0 + m; if (gm >= M) gm = M - 1;
      *(bf16x8*)&Ash[(k8 * 128 + m) * 8] = *(const bf16x8*)&A[(size_t)gm * D_H + k0 + k8 * 8];
    }
    {
      int nn = tid >> 2, k8 = tid & 3;
      *(bf16x8*)&Bsh[(k8 * 64 + nn) * 8] = *(const bf16x8*)&Bt[(size_t)nn * D_H + k0 + k8 * 8];
    }
    __syncthreads();
    bf16x8 af[2], bfv[4];
#pragma unroll
    for (int mf = 0; mf < 2; ++mf)
      af[mf] = *(const bf16x8*)&Ash[(quad * 128 + (wm + mf * 16 + l16)) * 8];
#pragma unroll
    for (int nf = 0; nf < 4; ++nf)
      bfv[nf] = *(const bf16x8*)&Bsh[(quad * 64 + (nf * 16 + l16)) * 8];
#pragma unroll
    for (int mf = 0; mf < 2; ++mf)
#pragma unroll
      for (int nf = 0; nf < 4; ++nf)
        acc[mf][nf] = __builtin_amdgcn_mfma_f32_16x16x32_bf16(af[mf], bfv[nf], acc[mf][nf], 0, 0, 0);
  }
#pragma unroll
  for (int mf = 0; mf < 2; ++mf)
#pragma unroll
    for (int nf = 0; nf < 4; ++nf)
#pragma unroll
      for (int i = 0; i < 4; ++i) {
        int r = m0 + wm + mf * 16 + quad * 4 + i;
        int cc = nf * 16 + l16;
        if (r < M) Cout[(size_t)r * 64 + cc] = f2bf(acc[mf][nf][i] + cvec[cc]);
      }
}

// ---- SpMM2: out(fp32) = adj @ hw + b1; half-wave/node, shfl edge broadcast --
__global__ __launch_bounds__(256) void k_spmm2(const unsigned int* __restrict__ hw2,
                                               const float* __restrict__ adj,
                                               const int* __restrict__ col,
                                               const int* __restrict__ rp,
                                               const float* __restrict__ b1,
                                               float2* __restrict__ o2, int n) {
  int node = blockIdx.x * 8 + (threadIdx.x >> 5);
  if (node >= n) return;
  int l = threadIdx.x & 31;
  int e0 = rp[node], e1 = rp[node + 1];
  float a0 = 0.f, a1 = 0.f;
  for (int e = e0; e < e1; e += 8) {
    int ee = e + (l & 7);
    int ec = ee < e1 ? ee : e1 - 1;
    int   cl = col[ec];
    float vl = ee < e1 ? adj[ec] : 0.f;
#pragma unroll
    for (int j = 0; j < 8; ++j) {
      int   cj = __shfl(cl, j, 32);
      float wj = __shfl(vl, j, 32);
      unsigned int p = hw2[(size_t)cj * 32 + l];
      a0 += wj * bf2f((unsigned short)(p & 0xFFFF));
      a1 += wj * bf2f((unsigned short)(p >> 16));
    }
  }
  float2 r; r.x = a0 + b1[2 * l]; r.y = a1 + b1[2 * l + 1];
  o2[(size_t)node * 32 + l] = r;
}

extern "C" void kernel_launch(void* const* d_in, const int* in_sizes, int n_in,
                              void* d_out, int out_size, void* d_ws, size_t ws_size,
                              hipStream_t stream) {
  const float* x   = (const float*)d_in[0];
  const float* W0  = (const float*)d_in[1];
  const float* b0  = (const float*)d_in[2];
  const float* W1  = (const float*)d_in[3];
  const float* b1  = (const float*)d_in[4];
  const float* adj = (const float*)d_in[5];
  const int* row = (const int*)d_in[6];
  const int* col = (const int*)d_in[7];
  const int N = in_sizes[0] / D_IN;
  const int E = in_sizes[5];

  char* ws = (char*)d_ws;
  int*            rp   = (int*)(ws + OFF_RP);
  unsigned short* W0t  = (unsigned short*)(ws + OFF_W0T);
  unsigned short* W1tp = (unsigned short*)(ws + OFF_W1TP);
  float*          cvec = (float*)(ws + OFF_CVEC);
  float*          psum = (float*)(ws + OFF_PSUM);
  float*          psq  = (float*)(ws + OFF_PSQ);
  unsigned short* h    = (unsigned short*)(ws + OFF_H);

  // xw (packed bf16 100000x128 = 25.6MB) overlays d_out (fp32 out = 25.6MB).
  unsigned short* xw = (unsigned short*)d_out;
  const bool hw_in_ws = (ws_size >= (size_t)END_HW);
  unsigned short* hwp  = hw_in_ws ? (unsigned short*)(ws + END_H) : (unsigned short*)d_out;
  float*          outd = hw_in_ws ? (float*)d_out                 : (float*)(ws + OFF_H);

  const int RB = (N + 1 + 255) / 256;
  const int TB = (D_IN * D_H) / 256;
  k_init<<<RB + TB, 256, 0, stream>>>(row, rp, W0, W0t, N, E, RB);
  k_gemm1<<<(N + 127) / 128, 256, 0, stream>>>(x, W0t, xw, N);
  k_spmm1<<<(N + 3) / 4, 256, 0, stream>>>((const unsigned int*)xw, adj, col, rp, b0,
                                           (unsigned int*)h, N);
  k_stats<<<SB, 256, 0, stream>>>((const unsigned int*)h, psum, psq, N);
  k_prep2<<<1, 256, 0, stream>>>(psum, psq, W1, W1tp, cvec, N);
  k_gemm2<<<(N + 127) / 128, 256, 0, stream>>>(h, W1tp, cvec, hwp, N);
  k_spmm2<<<(N + 7) / 8, 256, 0, stream>>>((const unsigned int*)hwp, adj, col, rp, b1,
                                           (float2*)outd, N);
  if (!hw_in_ws) {
    hipMemcpyAsync(d_out, outd, (size_t)N * D_OUT * sizeof(float),
                   hipMemcpyDeviceToDevice, stream);
  }
}